// Round 8
// baseline (197.227 us; speedup 1.0000x reference)
//
#include <hip/hip_runtime.h>
#include <hip/hip_bf16.h>

typedef __hip_bfloat16 bf16;
typedef __bf16 b16x8 __attribute__((ext_vector_type(8)));
typedef __bf16 b16x4 __attribute__((ext_vector_type(4)));
typedef float f32x4 __attribute__((ext_vector_type(4)));
typedef float f32x2 __attribute__((ext_vector_type(2)));

#define HWs   12800   // 80*160
#define NPIX  25600   // 2*80*160
#define IMG_H 80
#define IMG_W 160

// bf16 weight-cache element offsets inside wbuf
#define OFF_VCB  0        // 128x128
#define OFF_VGB  16384    // 128x128
#define OFF_MATB 32768    // 162x128  (wc|wg|kpc|kpg concatenated; +pad rows into OUTB, reads guarded)
#define OFF_OUTB 53504    // 128x256
#define NW_BF16  86272

// ---------------- k_prep: f32 -> bf16 weight cache + concatenated bias ----------------
__global__ __launch_bounds__(256) void k_prep(
    const float* __restrict__ vc_w, const float* __restrict__ vg_w,
    const float* __restrict__ wc_w, const float* __restrict__ wg_w,
    const float* __restrict__ kpc_w, const float* __restrict__ kpg_w,
    const float* __restrict__ out_w,
    const float* __restrict__ wc_b, const float* __restrict__ wg_b,
    const float* __restrict__ kpc_b, const float* __restrict__ kpg_b,
    bf16* __restrict__ wbuf, float* __restrict__ bias176)
{
    int i = blockIdx.x * 256 + threadIdx.x;
    if (i < 16384) {
        wbuf[i] = __float2bfloat16(vc_w[i]);
    } else if (i < 32768) {
        wbuf[i] = __float2bfloat16(vg_w[i - 16384]);
    } else if (i < 53504) {
        int j = i - 32768; int row = j >> 7; int c = j & 127;
        float v;
        if (row < 72)       v = wc_w[row * 128 + c];
        else if (row < 144) v = wg_w[(row - 72) * 128 + c];
        else if (row < 153) v = kpc_w[(row - 144) * 128 + c];
        else                v = kpg_w[(row - 153) * 128 + c];
        wbuf[i] = __float2bfloat16(v);
    } else if (i < NW_BF16) {
        wbuf[i] = __float2bfloat16(out_w[i - 53504]);
    } else if (i < NW_BF16 + 176) {
        int j = i - NW_BF16;
        float v = 0.f;
        if (j < 72)       v = wc_b[j];
        else if (j < 144) v = wg_b[j - 72];
        else if (j < 153) v = kpc_b[j - 144];
        else if (j < 162) v = kpg_b[j - 153];
        bias176[j] = v;
    }
}

// ---------------- Stage 1: fused LN + GEMMs (R6-measured-best shape: 32 px, 256 thr) ----------------
__global__ __launch_bounds__(256) void k_stage1(
    const float* __restrict__ match, const float* __restrict__ context, const float* __restrict__ geometric,
    const float* __restrict__ ln_g, const float* __restrict__ ln_b,
    const float* __restrict__ lnc_g, const float* __restrict__ lnc_b,
    const float* __restrict__ lng_g, const float* __restrict__ lng_b,
    const float* __restrict__ vc_b, const float* __restrict__ vg_b,
    const bf16* __restrict__ wbuf, const float* __restrict__ bias176,
    const float* __restrict__ anc_c, const float* __restrict__ anc_g,
    unsigned char* __restrict__ ctx8, unsigned char* __restrict__ geo8,
    bf16* __restrict__ wts_g, float* __restrict__ kp_out)
{
    __shared__ __align__(16) bf16 tile_s[32 * 136];
    __shared__ __align__(16) bf16 logit_s[32 * 148];   // seg2: logits; seg<2: reused as fp8 tile
    __shared__ float offs_s[32 * 18];
    __shared__ float red1[8][32];
    __shared__ float red2[8][32];

    unsigned char* fp8_s = (unsigned char*)logit_s;    // 4096 B needed, 9472 B available

    int bx = blockIdx.x;
    int seg = bx % 3;                    // 0 ctx, 1 geo, 2 match (interleaved)
    int tile = bx / 3;
    int t = threadIdx.x;
    int pixbase = tile * 32;

    const float* X  = (seg == 0) ? context : (seg == 1) ? geometric : match;
    const float* gg = (seg == 0) ? lnc_g   : (seg == 1) ? lng_g     : ln_g;
    const float* bb = (seg == 0) ? lnc_b   : (seg == 1) ? lng_b     : ln_b;

    // ---- issue LN global loads FIRST (oldest in vmcnt queue) ----
    int p = t & 31;
    int cq = t >> 5;
    int b = pixbase >= HWs;
    int hw = pixbase - b * HWs;
    const float* base = X + ((size_t)b * 128) * HWs + hw + p;
    float xv[16];
#pragma unroll
    for (int j = 0; j < 16; j++) xv[j] = base[(size_t)(cq * 16 + j) * HWs];

    // ---- prefetch this wave's W-fragments (bf16 wbuf, independent of LN) ----
    int wv = t >> 6;
    int lane = t & 63;
    int s = wv >> 1;                     // subtile of 16 pixels
    int h = wv & 1;                      // output-tile parity
    int lrow = lane & 15;
    int lq = lane >> 4;
    const bf16* Wb = (seg == 0) ? wbuf + OFF_VCB
                   : (seg == 1) ? wbuf + OFF_VGB
                                : wbuf + OFF_MATB;
    b16x8 wf[4][4];
#pragma unroll
    for (int i = 0; i < 4; i++) {
        int o = (h + 2 * i) * 16 + lrow;            // match: o <= 111 < 162, safe
        const bf16* wr = Wb + (size_t)o * 128;
#pragma unroll
        for (int kk = 0; kk < 4; kk++)
            wf[i][kk] = *(const b16x8*)(wr + (kk * 4 + lq) * 8);
    }

    // ---- LN reduce + normalized tile ----
    {
        float s1 = 0.f, s2 = 0.f;
#pragma unroll
        for (int j = 0; j < 16; j++) { s1 += xv[j]; s2 += xv[j] * xv[j]; }
        red1[cq][p] = s1; red2[cq][p] = s2;
        __syncthreads();
        float S1 = 0.f, S2 = 0.f;
#pragma unroll
        for (int q = 0; q < 8; q++) { S1 += red1[q][p]; S2 += red2[q][p]; }
        float mean = S1 * (1.f / 128.f);
        float var  = fmaxf(S2 * (1.f / 128.f) - mean * mean, 0.f);
        float rstd = rsqrtf(var + 1e-5f);
#pragma unroll
        for (int j = 0; j < 16; j++) {
            int c = cq * 16 + j;
            float y = (xv[j] - mean) * rstd * gg[c] + bb[c];
            tile_s[p * 136 + c] = __float2bfloat16(y);
        }
        __syncthreads();
    }

    // ---- A fragments (normalized pixels) ----
    const b16x8* arow = (const b16x8*)(tile_s + (s * 16 + lrow) * 136);
    b16x8 af[4];
#pragma unroll
    for (int kk = 0; kk < 4; kk++) af[kk] = arow[kk * 4 + lq];

    int prow = s * 16 + lrow;            // this lane's pixel (C/D column after operand swap)

    if (seg < 2) {
        unsigned char* val = (seg == 0) ? ctx8 : geo8;
        const float* vb = (seg == 0) ? vc_b : vg_b;
        int swz = (prow & 7) << 4;       // 16B-unit XOR swizzle breaks stride-128 bank conflict
#pragma unroll
        for (int i = 0; i < 4; i++) {
            int obase = (h + 2 * i) * 16 + lq * 4;              // 4 consecutive channels
            f32x4 acc = {0.f, 0.f, 0.f, 0.f};
#pragma unroll
            for (int kk = 0; kk < 4; kk++)
                acc = __builtin_amdgcn_mfma_f32_16x16x32_bf16(wf[i][kk], af[kk], acc, 0, 0, 0);
            f32x4 bv = *(const f32x4*)(vb + obase);
            int u = __builtin_amdgcn_cvt_pk_fp8_f32(acc[0] + bv[0], acc[1] + bv[1], 0, false);
            u = __builtin_amdgcn_cvt_pk_fp8_f32(acc[2] + bv[2], acc[3] + bv[3], u, true);
            *(unsigned int*)(fp8_s + prow * 128 + (obase ^ swz)) = (unsigned int)u;
        }
        __syncthreads();
        // coalesced copy-out: one uint4/thread, 1KB contiguous per wave
        int row = t >> 3;
        int col = t & 7;
        uint4 v4 = *(const uint4*)(fp8_s + row * 128 + ((col ^ (row & 7)) * 16));
        *(uint4*)(val + (size_t)(pixbase + row) * 128 + col * 16) = v4;
        return;
    }

    // ---- seg == 2: match branch ----
#pragma unroll
    for (int i = 0; i < 4; i++) {
        int obase = (h + 2 * i) * 16 + lq * 4;
        f32x4 acc = {0.f, 0.f, 0.f, 0.f};
#pragma unroll
        for (int kk = 0; kk < 4; kk++)
            acc = __builtin_amdgcn_mfma_f32_16x16x32_bf16(wf[i][kk], af[kk], acc, 0, 0, 0);
        f32x4 bv = *(const f32x4*)(bias176 + obase);
        b16x4 pk4;
#pragma unroll
        for (int r = 0; r < 4; r++) pk4[r] = (__bf16)(acc[r] + bv[r]);
        *(b16x4*)(logit_s + prow * 148 + obase) = pk4;
    }
    for (int ot = h + 8; ot < 11; ot += 2) {        // h=0: 8,10 ; h=1: 9
        int obase = ot * 16 + lq * 4;
        const bf16* wr = Wb + (size_t)(ot * 16 + lrow) * 128;   // reads padded rows, stores guarded
        f32x4 acc = {0.f, 0.f, 0.f, 0.f};
#pragma unroll
        for (int kk = 0; kk < 4; kk++)
            acc = __builtin_amdgcn_mfma_f32_16x16x32_bf16(*(const b16x8*)(wr + (kk * 4 + lq) * 8), af[kk], acc, 0, 0, 0);
        f32x4 bv = *(const f32x4*)(bias176 + obase);
        if (ot == 8) {                              // o in [128,144) -> logits
            b16x4 pk4;
#pragma unroll
            for (int r = 0; r < 4; r++) pk4[r] = (__bf16)(acc[r] + bv[r]);
            *(b16x4*)(logit_s + prow * 148 + obase) = pk4;
        } else if (ot == 9) {                       // o in [144,160) -> offsets 0..15
#pragma unroll
            for (int r = 0; r < 4; r++)
                offs_s[prow * 18 + (obase - 144) + r] = acc[r] + bv[r];
        } else {                                    // ot == 10: only o=160,161 valid
            if (lq == 0) {
                offs_s[prow * 18 + 16] = acc[0] + bv[0];
                offs_s[prow * 18 + 17] = acc[1] + bv[1];
            }
        }
    }
    __syncthreads();

    // softmax over P per (pixel, branch, group): 512 tasks
#pragma unroll
    for (int i = 0; i < 2; i++) {
        int task = t + 256 * i;
        int lp = task >> 4;
        int sub = task & 15;
        int br = sub >> 3;
        int g = sub & 7;
        const bf16* basel = logit_s + lp * 148 + br * 72 + g;   // channel c = p*8+g
        float v[9];
        float m = -1e30f;
#pragma unroll
        for (int pp = 0; pp < 9; pp++) { v[pp] = __bfloat162float(basel[pp * 8]); m = fmaxf(m, v[pp]); }
        float ssum = 0.f;
#pragma unroll
        for (int pp = 0; pp < 9; pp++) { v[pp] = __expf(v[pp] - m); ssum += v[pp]; }
        float inv = 1.f / ssum;
        int pix = pixbase + lp;
        bf16* wbp = wts_g + ((size_t)pix * 2 + br) * 72 + g * 9;
#pragma unroll
        for (int pp = 0; pp < 9; pp++) wbp[pp] = __float2bfloat16(v[pp] * inv);
    }

    // keypoints: 576 tasks (kp_out f32 = ref output dtype; k_fuse re-derives coords)
    for (int i = 0; i < 3; i++) {
        int task = t + 256 * i;
        if (task < 576) {
            int lp = task / 18;
            int sub2 = task - lp * 18;
            int br = sub2 / 9;
            int pp = sub2 - br * 9;
            int pix = pixbase + lp;
            float off = offs_s[lp * 18 + br * 9 + pp];
            const float* anc = br ? anc_g : anc_c;
            f32x2 a2 = *(const f32x2*)(anc + (size_t)pix * 18 + pp * 2);
            f32x2 kp2 = {a2[0] + off, a2[1]};
            *(f32x2*)(kp_out + (size_t)br * (NPIX * 18) + (size_t)pix * 18 + pp * 2) = kp2;
        }
    }
}

// ---- k_fuse gather pipeline macros ----
#define KF_ISSUE(PP, U, CW) do {                                               \
    float px = cc[PP][0] * 160.f - 0.5f;                                       \
    float py = cc[PP][1] * 80.f - 0.5f;                                        \
    float fx = floorf(px), fy = floorf(py);                                    \
    float dx = px - fx, dy = py - fy;                                          \
    int x0 = (int)fx, y0 = (int)fy;                                            \
    float wt = wtv[PP];                                                        \
    _Pragma("unroll")                                                          \
    for (int c4 = 0; c4 < 4; c4++) {                                           \
        int xi = x0 + (c4 & 1);                                                \
        int yi = y0 + (c4 >> 1);                                               \
        bool ok = (xi >= 0) & (xi < IMG_W) & (yi >= 0) & (yi < IMG_H);         \
        int xc = min(max(xi, 0), IMG_W - 1);                                   \
        int yc = min(max(yi, 0), IMG_H - 1);                                   \
        float wx = (c4 & 1) ? dx : 1.f - dx;                                   \
        float wy = (c4 >> 1) ? dy : 1.f - dy;                                  \
        CW[c4] = ok ? wx * wy * wt : 0.f;                                      \
        U[c4] = *(const uint2*)(val + (size_t)(rowbase + yc * IMG_W + xc) * 128 + c0); \
    }                                                                          \
} while (0)

#define KF_CONSUME(U, CW) do {                                                 \
    _Pragma("unroll")                                                          \
    for (int c4 = 0; c4 < 4; c4++) {                                           \
        float wgt = CW[c4];                                                    \
        f32x2 v01 = __builtin_amdgcn_cvt_pk_f32_fp8(U[c4].x, false);           \
        f32x2 v23 = __builtin_amdgcn_cvt_pk_f32_fp8(U[c4].x, true);            \
        f32x2 v45 = __builtin_amdgcn_cvt_pk_f32_fp8(U[c4].y, false);           \
        f32x2 v67 = __builtin_amdgcn_cvt_pk_f32_fp8(U[c4].y, true);            \
        acc[0] += wgt * v01[0]; acc[1] += wgt * v01[1];                        \
        acc[2] += wgt * v23[0]; acc[3] += wgt * v23[1];                        \
        acc[4] += wgt * v45[0]; acc[5] += wgt * v45[1];                        \
        acc[6] += wgt * v67[0]; acc[7] += wgt * v67[1];                        \
    }                                                                          \
} while (0)

// ---------------- fused bilinear gather (fp8) + aggregate + output projection ----------------
// R6-proven structure; pipeline deepened 3 -> 4 points (16 loads in flight). Consumption
// order remains p=0..8 sequential -> bit-identical accumulation. min-waves=4 keeps the
// VGPR budget at 128 so the compiler doesn't trade ILP for occupancy (R5 lesson).
__global__ __launch_bounds__(256, 4) void k_fuse(
    const unsigned char* __restrict__ ctx8, const unsigned char* __restrict__ geo8,
    const bf16* __restrict__ wts_g, const float* __restrict__ kp_out,
    const float* __restrict__ mask,
    const bf16* __restrict__ outb, const float* __restrict__ out_b,
    float* __restrict__ out)
{
    __shared__ __align__(16) bf16 agg_s[16 * 264];   // stride 264: bank-spread for b128 r/w

    int t = threadIdx.x;
    int wv = t >> 6;
    int lane = t & 63;
    int q = lane >> 4;           // quarter-wave task slot
    int sub = lane & 15;         // channel octet
    int c0 = sub * 8;
    int g = sub >> 1;            // group = c/16

    int pixbase = blockIdx.x * 16;           // 1600 blocks; never straddles batch
    int qw = wv * 4 + q;                     // 0..15
    int pix = pixbase + qw;
    int b = pixbase >= HWs;
    int rowbase = b * HWs;

    float mv0 = mask[pix];                   // hoisted (br=0 scale)

#pragma unroll
    for (int br = 0; br < 2; br++) {
        const unsigned char* val = br ? geo8 : ctx8;
        const bf16* wb = wts_g + (size_t)(pix * 2 + br) * 72 + g * 9;
        const float* cb = kp_out + (size_t)br * (NPIX * 18) + (size_t)pix * 18;

        // ---- preload ALL coords + weights (18 independent loads issued together) ----
        f32x2 cc[9];
#pragma unroll
        for (int pp = 0; pp < 9; pp++) cc[pp] = *(const f32x2*)(cb + pp * 2);
        float wtv[9];
#pragma unroll
        for (int pp = 0; pp < 9; pp++) wtv[pp] = __bfloat162float(wb[pp]);

        float acc[8] = {0.f, 0.f, 0.f, 0.f, 0.f, 0.f, 0.f, 0.f};

        // ---- depth-4 software pipeline over the 9 points (16 loads in flight) ----
        uint2 u0[4], u1[4], u2[4], u3[4];
        float cw0[4], cw1[4], cw2[4], cw3[4];
        KF_ISSUE(0, u0, cw0);
        KF_ISSUE(1, u1, cw1);
        KF_ISSUE(2, u2, cw2);
        KF_ISSUE(3, u3, cw3);
        KF_CONSUME(u0, cw0); KF_ISSUE(4, u0, cw0);
        KF_CONSUME(u1, cw1); KF_ISSUE(5, u1, cw1);
        KF_CONSUME(u2, cw2); KF_ISSUE(6, u2, cw2);
        KF_CONSUME(u3, cw3); KF_ISSUE(7, u3, cw3);
        KF_CONSUME(u0, cw0); KF_ISSUE(8, u0, cw0);
        KF_CONSUME(u1, cw1);
        KF_CONSUME(u2, cw2);
        KF_CONSUME(u3, cw3);
        KF_CONSUME(u0, cw0);

        float mv = (br == 0) ? mv0 : 1.f;
        b16x8 pk;
#pragma unroll
        for (int j = 0; j < 8; j++) pk[j] = (__bf16)(acc[j] * mv);
        *(b16x8*)(agg_s + qw * 264 + br * 128 + c0) = pk;
    }
    __syncthreads();

    // ---- projection: 16 pix x 128 out, K=256 (bf16 outb) ----
    int lrow = lane & 15;
    int lq = lane >> 4;
    b16x8 af[8];
#pragma unroll
    for (int kk = 0; kk < 8; kk++)
        af[kk] = *(const b16x8*)(agg_s + lrow * 264 + (kk * 4 + lq) * 8);
#pragma unroll
    for (int i = 0; i < 2; i++) {
        int o = (wv + 4 * i) * 16 + lrow;
        const bf16* wrow = outb + (size_t)o * 256;
        f32x4 acc4 = {0.f, 0.f, 0.f, 0.f};
#pragma unroll
        for (int kk = 0; kk < 8; kk++)
            acc4 = __builtin_amdgcn_mfma_f32_16x16x32_bf16(af[kk], *(const b16x8*)(wrow + (kk * 4 + lq) * 8), acc4, 0, 0, 0);
        float bias = out_b[o];
        f32x4 st;
#pragma unroll
        for (int r = 0; r < 4; r++) st[r] = acc4[r] + bias;
        int hw0 = pixbase + lq * 4 - rowbase;       // pix = pixbase + lq*4 + r -> consecutive hw
        *(f32x4*)(out + (size_t)b * (128 * HWs) + (size_t)o * HWs + hw0) = st;
    }
}

extern "C" void kernel_launch(void* const* d_in, const int* in_sizes, int n_in,
                              void* d_out, int out_size, void* d_ws, size_t ws_size,
                              hipStream_t stream)
{
    const float* mask      = (const float*)d_in[0];
    const float* match     = (const float*)d_in[1];
    const float* context   = (const float*)d_in[2];
    const float* geometric = (const float*)d_in[3];
    const float* anc_c     = (const float*)d_in[4];
    const float* anc_g     = (const float*)d_in[5];
    const float* ln_g  = (const float*)d_in[6];
    const float* ln_b  = (const float*)d_in[7];
    const float* lnc_g = (const float*)d_in[8];
    const float* lnc_b = (const float*)d_in[9];
    const float* lng_g = (const float*)d_in[10];
    const float* lng_b = (const float*)d_in[11];
    const float* wc_w  = (const float*)d_in[12];
    const float* wc_b  = (const float*)d_in[13];
    const float* wg_w  = (const float*)d_in[14];
    const float* wg_b  = (const float*)d_in[15];
    const float* vc_w  = (const float*)d_in[16];
    const float* vc_b  = (const float*)d_in[17];
    const float* vg_w  = (const float*)d_in[18];
    const float* vg_b  = (const float*)d_in[19];
    const float* out_w = (const float*)d_in[20];
    const float* out_b = (const float*)d_in[21];
    const float* kpc_w = (const float*)d_in[22];
    const float* kpc_b = (const float*)d_in[23];
    const float* kpg_w = (const float*)d_in[24];
    const float* kpg_b = (const float*)d_in[25];

    // d_ws layout
    char* w = (char*)d_ws;
    unsigned char* ctx8 = (unsigned char*)(w);            //  3,276,800 B (fp8)
    unsigned char* geo8 = (unsigned char*)(w + 3276800);  //  3,276,800 B
    bf16*  wts_g    = (bf16*)(w + 6553600);               //  7,372,800 B
    bf16*  wbuf     = (bf16*)(w + 13926400);              //    172,544 B
    float* bias176  = (float*)(w + 14098944);             //        704 B

    float* outp = (float*)d_out;
    float* kp_out = outp + (size_t)2 * 128 * HWs;         // outputs are f32 (ref dtype)

    k_prep<<<(NW_BF16 + 176 + 255) / 256, 256, 0, stream>>>(
        vc_w, vg_w, wc_w, wg_w, kpc_w, kpg_w, out_w,
        wc_b, wg_b, kpc_b, kpg_b, wbuf, bias176);
    k_stage1<<<2400, 256, 0, stream>>>(match, context, geometric,
                                       ln_g, ln_b, lnc_g, lnc_b, lng_g, lng_b,
                                       vc_b, vg_b, wbuf, bias176,
                                       anc_c, anc_g,
                                       ctx8, geo8, wts_g, kp_out);
    k_fuse<<<1600, 256, 0, stream>>>(ctx8, geo8, wts_g, kp_out, mask,
                                     wbuf + OFF_OUTB, out_b, outp);
}

// Round 9
// 194.328 us; speedup vs baseline: 1.0149x; 1.0149x over previous
//
#include <hip/hip_runtime.h>
#include <hip/hip_bf16.h>

typedef __hip_bfloat16 bf16;
typedef __bf16 b16x8 __attribute__((ext_vector_type(8)));
typedef __bf16 b16x4 __attribute__((ext_vector_type(4)));
typedef float f32x4 __attribute__((ext_vector_type(4)));
typedef float f32x2 __attribute__((ext_vector_type(2)));

#define HWs   12800   // 80*160
#define NPIX  25600   // 2*80*160
#define IMG_H 80
#define IMG_W 160

// bf16 weight-cache element offsets inside wbuf
#define OFF_VCB  0        // 128x128
#define OFF_VGB  16384    // 128x128
#define OFF_MATB 32768    // 162x128  (wc|wg|kpc|kpg concatenated; +pad rows into OUTB, reads guarded)
#define OFF_OUTB 53504    // 128x256
#define NW_BF16  86272

// ---------------- k_prep: f32 -> bf16 weight cache + concatenated bias ----------------
__global__ __launch_bounds__(256) void k_prep(
    const float* __restrict__ vc_w, const float* __restrict__ vg_w,
    const float* __restrict__ wc_w, const float* __restrict__ wg_w,
    const float* __restrict__ kpc_w, const float* __restrict__ kpg_w,
    const float* __restrict__ out_w,
    const float* __restrict__ wc_b, const float* __restrict__ wg_b,
    const float* __restrict__ kpc_b, const float* __restrict__ kpg_b,
    bf16* __restrict__ wbuf, float* __restrict__ bias176)
{
    int i = blockIdx.x * 256 + threadIdx.x;
    if (i < 16384) {
        wbuf[i] = __float2bfloat16(vc_w[i]);
    } else if (i < 32768) {
        wbuf[i] = __float2bfloat16(vg_w[i - 16384]);
    } else if (i < 53504) {
        int j = i - 32768; int row = j >> 7; int c = j & 127;
        float v;
        if (row < 72)       v = wc_w[row * 128 + c];
        else if (row < 144) v = wg_w[(row - 72) * 128 + c];
        else if (row < 153) v = kpc_w[(row - 144) * 128 + c];
        else                v = kpg_w[(row - 153) * 128 + c];
        wbuf[i] = __float2bfloat16(v);
    } else if (i < NW_BF16) {
        wbuf[i] = __float2bfloat16(out_w[i - 53504]);
    } else if (i < NW_BF16 + 176) {
        int j = i - NW_BF16;
        float v = 0.f;
        if (j < 72)       v = wc_b[j];
        else if (j < 144) v = wg_b[j - 72];
        else if (j < 153) v = kpc_b[j - 144];
        else if (j < 162) v = kpg_b[j - 153];
        bias176[j] = v;
    }
}

// ---------------- Stage 1: fused LN + GEMMs ----------------
// R8 diagnosis: stage1 pinned at 0.91 TB/s with 16 scalar dword loads/thread. R7 falsified
// segment WIDTH as the limiter; this round tests request COUNT: f32x2 loads (8B/lane,
// 2 pixels x 8 channels per thread) halve the VMEM request count at constant bytes.
__global__ __launch_bounds__(256) void k_stage1(
    const float* __restrict__ match, const float* __restrict__ context, const float* __restrict__ geometric,
    const float* __restrict__ ln_g, const float* __restrict__ ln_b,
    const float* __restrict__ lnc_g, const float* __restrict__ lnc_b,
    const float* __restrict__ lng_g, const float* __restrict__ lng_b,
    const float* __restrict__ vc_b, const float* __restrict__ vg_b,
    const bf16* __restrict__ wbuf, const float* __restrict__ bias176,
    const float* __restrict__ anc_c, const float* __restrict__ anc_g,
    unsigned char* __restrict__ ctx8, unsigned char* __restrict__ geo8,
    bf16* __restrict__ wts_g, float* __restrict__ kp_out)
{
    __shared__ __align__(16) bf16 tile_s[32 * 136];
    __shared__ __align__(16) bf16 logit_s[32 * 148];   // seg2: logits; seg<2: reused as fp8 tile
    __shared__ float offs_s[32 * 18];
    __shared__ float red1[16][32];
    __shared__ float red2[16][32];
    __shared__ f32x2 stat_s[32];                        // per-pixel {mean, rstd}

    unsigned char* fp8_s = (unsigned char*)logit_s;    // 4096 B needed, 9472 B available

    int bx = blockIdx.x;
    int seg = bx % 3;                    // 0 ctx, 1 geo, 2 match (interleaved)
    int tile = bx / 3;
    int t = threadIdx.x;
    int pixbase = tile * 32;

    const float* X  = (seg == 0) ? context : (seg == 1) ? geometric : match;
    const float* gg = (seg == 0) ? lnc_g   : (seg == 1) ? lng_g     : ln_g;
    const float* bb = (seg == 0) ? lnc_b   : (seg == 1) ? lng_b     : ln_b;

    // ---- issue LN global loads FIRST (oldest in vmcnt queue) ----
    // thread = (pixel-pair ph, 8-channel group cq8): 8 x f32x2 loads (8B/lane).
    int ph  = t & 15;                    // pixel pair -> pixels 2ph, 2ph+1
    int cq8 = t >> 4;                    // channels cq8*8 .. cq8*8+7
    int b = pixbase >= HWs;
    int hw = pixbase - b * HWs;
    const float* base2 = X + ((size_t)b * 128) * HWs + hw + 2 * ph;
    f32x2 xv[8];
#pragma unroll
    for (int j = 0; j < 8; j++) xv[j] = *(const f32x2*)(base2 + (size_t)(cq8 * 8 + j) * HWs);

    // ---- prefetch this wave's W-fragments (bf16 wbuf, independent of LN) ----
    int wv = t >> 6;
    int lane = t & 63;
    int s = wv >> 1;                     // subtile of 16 pixels
    int h = wv & 1;                      // output-tile parity
    int lrow = lane & 15;
    int lq = lane >> 4;
    const bf16* Wb = (seg == 0) ? wbuf + OFF_VCB
                   : (seg == 1) ? wbuf + OFF_VGB
                                : wbuf + OFF_MATB;
    b16x8 wf[4][4];
#pragma unroll
    for (int i = 0; i < 4; i++) {
        int o = (h + 2 * i) * 16 + lrow;            // match: o <= 111 < 162, safe
        const bf16* wr = Wb + (size_t)o * 128;
#pragma unroll
        for (int kk = 0; kk < 4; kk++)
            wf[i][kk] = *(const b16x8*)(wr + (kk * 4 + lq) * 8);
    }

    // ---- LN reduce + normalized tile ----
    {
        float s1a = 0.f, s2a = 0.f, s1b = 0.f, s2b = 0.f;
#pragma unroll
        for (int j = 0; j < 8; j++) {
            float a = xv[j][0], c = xv[j][1];
            s1a += a; s2a += a * a;
            s1b += c; s2b += c * c;
        }
        red1[cq8][2 * ph]     = s1a; red2[cq8][2 * ph]     = s2a;
        red1[cq8][2 * ph + 1] = s1b; red2[cq8][2 * ph + 1] = s2b;
        __syncthreads();
        if (t < 32) {
            float S1 = 0.f, S2 = 0.f;
#pragma unroll
            for (int q = 0; q < 16; q++) { S1 += red1[q][t]; S2 += red2[q][t]; }
            float mean = S1 * (1.f / 128.f);
            float var  = fmaxf(S2 * (1.f / 128.f) - mean * mean, 0.f);
            f32x2 st; st[0] = mean; st[1] = rsqrtf(var + 1e-5f);
            stat_s[t] = st;
        }
        __syncthreads();
        f32x2 st0 = stat_s[2 * ph];
        f32x2 st1 = stat_s[2 * ph + 1];
#pragma unroll
        for (int j = 0; j < 8; j++) {
            int c = cq8 * 8 + j;
            float gv = gg[c], bv = bb[c];
            tile_s[(2 * ph)     * 136 + c] = __float2bfloat16((xv[j][0] - st0[0]) * st0[1] * gv + bv);
            tile_s[(2 * ph + 1) * 136 + c] = __float2bfloat16((xv[j][1] - st1[0]) * st1[1] * gv + bv);
        }
        __syncthreads();
    }

    // ---- A fragments (normalized pixels) ----
    const b16x8* arow = (const b16x8*)(tile_s + (s * 16 + lrow) * 136);
    b16x8 af[4];
#pragma unroll
    for (int kk = 0; kk < 4; kk++) af[kk] = arow[kk * 4 + lq];

    int prow = s * 16 + lrow;            // this lane's pixel (C/D column after operand swap)

    if (seg < 2) {
        unsigned char* val = (seg == 0) ? ctx8 : geo8;
        const float* vb = (seg == 0) ? vc_b : vg_b;
        int swz = (prow & 7) << 4;       // 16B-unit XOR swizzle breaks stride-128 bank conflict
#pragma unroll
        for (int i = 0; i < 4; i++) {
            int obase = (h + 2 * i) * 16 + lq * 4;              // 4 consecutive channels
            f32x4 acc = {0.f, 0.f, 0.f, 0.f};
#pragma unroll
            for (int kk = 0; kk < 4; kk++)
                acc = __builtin_amdgcn_mfma_f32_16x16x32_bf16(wf[i][kk], af[kk], acc, 0, 0, 0);
            f32x4 bv = *(const f32x4*)(vb + obase);
            int u = __builtin_amdgcn_cvt_pk_fp8_f32(acc[0] + bv[0], acc[1] + bv[1], 0, false);
            u = __builtin_amdgcn_cvt_pk_fp8_f32(acc[2] + bv[2], acc[3] + bv[3], u, true);
            *(unsigned int*)(fp8_s + prow * 128 + (obase ^ swz)) = (unsigned int)u;
        }
        __syncthreads();
        // coalesced copy-out: one uint4/thread, 1KB contiguous per wave
        int row = t >> 3;
        int col = t & 7;
        uint4 v4 = *(const uint4*)(fp8_s + row * 128 + ((col ^ (row & 7)) * 16));
        *(uint4*)(val + (size_t)(pixbase + row) * 128 + col * 16) = v4;
        return;
    }

    // ---- seg == 2: match branch ----
#pragma unroll
    for (int i = 0; i < 4; i++) {
        int obase = (h + 2 * i) * 16 + lq * 4;
        f32x4 acc = {0.f, 0.f, 0.f, 0.f};
#pragma unroll
        for (int kk = 0; kk < 4; kk++)
            acc = __builtin_amdgcn_mfma_f32_16x16x32_bf16(wf[i][kk], af[kk], acc, 0, 0, 0);
        f32x4 bv = *(const f32x4*)(bias176 + obase);
        b16x4 pk4;
#pragma unroll
        for (int r = 0; r < 4; r++) pk4[r] = (__bf16)(acc[r] + bv[r]);
        *(b16x4*)(logit_s + prow * 148 + obase) = pk4;
    }
    for (int ot = h + 8; ot < 11; ot += 2) {        // h=0: 8,10 ; h=1: 9
        int obase = ot * 16 + lq * 4;
        const bf16* wr = Wb + (size_t)(ot * 16 + lrow) * 128;   // reads padded rows, stores guarded
        f32x4 acc = {0.f, 0.f, 0.f, 0.f};
#pragma unroll
        for (int kk = 0; kk < 4; kk++)
            acc = __builtin_amdgcn_mfma_f32_16x16x32_bf16(*(const b16x8*)(wr + (kk * 4 + lq) * 8), af[kk], acc, 0, 0, 0);
        f32x4 bv = *(const f32x4*)(bias176 + obase);
        if (ot == 8) {                              // o in [128,144) -> logits
            b16x4 pk4;
#pragma unroll
            for (int r = 0; r < 4; r++) pk4[r] = (__bf16)(acc[r] + bv[r]);
            *(b16x4*)(logit_s + prow * 148 + obase) = pk4;
        } else if (ot == 9) {                       // o in [144,160) -> offsets 0..15
#pragma unroll
            for (int r = 0; r < 4; r++)
                offs_s[prow * 18 + (obase - 144) + r] = acc[r] + bv[r];
        } else {                                    // ot == 10: only o=160,161 valid
            if (lq == 0) {
                offs_s[prow * 18 + 16] = acc[0] + bv[0];
                offs_s[prow * 18 + 17] = acc[1] + bv[1];
            }
        }
    }
    __syncthreads();

    // softmax over P per (pixel, branch, group): 512 tasks
#pragma unroll
    for (int i = 0; i < 2; i++) {
        int task = t + 256 * i;
        int lp = task >> 4;
        int sub = task & 15;
        int br = sub >> 3;
        int g = sub & 7;
        const bf16* basel = logit_s + lp * 148 + br * 72 + g;   // channel c = p*8+g
        float v[9];
        float m = -1e30f;
#pragma unroll
        for (int pp = 0; pp < 9; pp++) { v[pp] = __bfloat162float(basel[pp * 8]); m = fmaxf(m, v[pp]); }
        float ssum = 0.f;
#pragma unroll
        for (int pp = 0; pp < 9; pp++) { v[pp] = __expf(v[pp] - m); ssum += v[pp]; }
        float inv = 1.f / ssum;
        int pix = pixbase + lp;
        bf16* wbp = wts_g + ((size_t)pix * 2 + br) * 72 + g * 9;
#pragma unroll
        for (int pp = 0; pp < 9; pp++) wbp[pp] = __float2bfloat16(v[pp] * inv);
    }

    // keypoints: 576 tasks (kp_out f32 = ref output dtype; k_fuse re-derives coords)
    for (int i = 0; i < 3; i++) {
        int task = t + 256 * i;
        if (task < 576) {
            int lp = task / 18;
            int sub2 = task - lp * 18;
            int br = sub2 / 9;
            int pp = sub2 - br * 9;
            int pix = pixbase + lp;
            float off = offs_s[lp * 18 + br * 9 + pp];
            const float* anc = br ? anc_g : anc_c;
            f32x2 a2 = *(const f32x2*)(anc + (size_t)pix * 18 + pp * 2);
            f32x2 kp2 = {a2[0] + off, a2[1]};
            *(f32x2*)(kp_out + (size_t)br * (NPIX * 18) + (size_t)pix * 18 + pp * 2) = kp2;
        }
    }
}

// ---- k_fuse gather pipeline macros ----
#define KF_ISSUE(PP, U, CW) do {                                               \
    float px = cc[PP][0] * 160.f - 0.5f;                                       \
    float py = cc[PP][1] * 80.f - 0.5f;                                        \
    float fx = floorf(px), fy = floorf(py);                                    \
    float dx = px - fx, dy = py - fy;                                          \
    int x0 = (int)fx, y0 = (int)fy;                                            \
    float wt = wtv[PP];                                                        \
    _Pragma("unroll")                                                          \
    for (int c4 = 0; c4 < 4; c4++) {                                           \
        int xi = x0 + (c4 & 1);                                                \
        int yi = y0 + (c4 >> 1);                                               \
        bool ok = (xi >= 0) & (xi < IMG_W) & (yi >= 0) & (yi < IMG_H);         \
        int xc = min(max(xi, 0), IMG_W - 1);                                   \
        int yc = min(max(yi, 0), IMG_H - 1);                                   \
        float wx = (c4 & 1) ? dx : 1.f - dx;                                   \
        float wy = (c4 >> 1) ? dy : 1.f - dy;                                  \
        CW[c4] = ok ? wx * wy * wt : 0.f;                                      \
        U[c4] = *(const uint2*)(val + (size_t)(rowbase + yc * IMG_W + xc) * 128 + c0); \
    }                                                                          \
} while (0)

#define KF_CONSUME(U, CW) do {                                                 \
    _Pragma("unroll")                                                          \
    for (int c4 = 0; c4 < 4; c4++) {                                           \
        float wgt = CW[c4];                                                    \
        f32x2 v01 = __builtin_amdgcn_cvt_pk_f32_fp8(U[c4].x, false);           \
        f32x2 v23 = __builtin_amdgcn_cvt_pk_f32_fp8(U[c4].x, true);            \
        f32x2 v45 = __builtin_amdgcn_cvt_pk_f32_fp8(U[c4].y, false);           \
        f32x2 v67 = __builtin_amdgcn_cvt_pk_f32_fp8(U[c4].y, true);            \
        acc[0] += wgt * v01[0]; acc[1] += wgt * v01[1];                        \
        acc[2] += wgt * v23[0]; acc[3] += wgt * v23[1];                        \
        acc[4] += wgt * v45[0]; acc[5] += wgt * v45[1];                        \
        acc[6] += wgt * v67[0]; acc[7] += wgt * v67[1];                        \
    }                                                                          \
} while (0)

// ---------------- fused bilinear gather (fp8) + aggregate + output projection ----------------
// R6-measured-best form: quarter-wave per pixel, sequential br (L2 phasing), depth-3
// point pipeline (12 loads in flight), min-waves=4 (R5 lesson: don't let the compiler
// trade ILP registers for occupancy).
__global__ __launch_bounds__(256, 4) void k_fuse(
    const unsigned char* __restrict__ ctx8, const unsigned char* __restrict__ geo8,
    const bf16* __restrict__ wts_g, const float* __restrict__ kp_out,
    const float* __restrict__ mask,
    const bf16* __restrict__ outb, const float* __restrict__ out_b,
    float* __restrict__ out)
{
    __shared__ __align__(16) bf16 agg_s[16 * 264];   // stride 264: bank-spread for b128 r/w

    int t = threadIdx.x;
    int wv = t >> 6;
    int lane = t & 63;
    int q = lane >> 4;           // quarter-wave task slot
    int sub = lane & 15;         // channel octet
    int c0 = sub * 8;
    int g = sub >> 1;            // group = c/16

    int pixbase = blockIdx.x * 16;           // 1600 blocks; never straddles batch
    int qw = wv * 4 + q;                     // 0..15
    int pix = pixbase + qw;
    int b = pixbase >= HWs;
    int rowbase = b * HWs;

    float mv0 = mask[pix];                   // hoisted (br=0 scale)

#pragma unroll
    for (int br = 0; br < 2; br++) {
        const unsigned char* val = br ? geo8 : ctx8;
        const bf16* wb = wts_g + (size_t)(pix * 2 + br) * 72 + g * 9;
        const float* cb = kp_out + (size_t)br * (NPIX * 18) + (size_t)pix * 18;

        // ---- preload ALL coords + weights (18 independent loads issued together) ----
        f32x2 cc[9];
#pragma unroll
        for (int pp = 0; pp < 9; pp++) cc[pp] = *(const f32x2*)(cb + pp * 2);
        float wtv[9];
#pragma unroll
        for (int pp = 0; pp < 9; pp++) wtv[pp] = __bfloat162float(wb[pp]);

        float acc[8] = {0.f, 0.f, 0.f, 0.f, 0.f, 0.f, 0.f, 0.f};

        // ---- depth-3 software pipeline over the 9 points (12 loads in flight) ----
        uint2 u0[4], u1[4], u2[4];
        float cw0[4], cw1[4], cw2[4];
        KF_ISSUE(0, u0, cw0);
        KF_ISSUE(1, u1, cw1);
        KF_ISSUE(2, u2, cw2);
        KF_CONSUME(u0, cw0); KF_ISSUE(3, u0, cw0);
        KF_CONSUME(u1, cw1); KF_ISSUE(4, u1, cw1);
        KF_CONSUME(u2, cw2); KF_ISSUE(5, u2, cw2);
        KF_CONSUME(u0, cw0); KF_ISSUE(6, u0, cw0);
        KF_CONSUME(u1, cw1); KF_ISSUE(7, u1, cw1);
        KF_CONSUME(u2, cw2); KF_ISSUE(8, u2, cw2);
        KF_CONSUME(u0, cw0);
        KF_CONSUME(u1, cw1);
        KF_CONSUME(u2, cw2);

        float mv = (br == 0) ? mv0 : 1.f;
        b16x8 pk;
#pragma unroll
        for (int j = 0; j < 8; j++) pk[j] = (__bf16)(acc[j] * mv);
        *(b16x8*)(agg_s + qw * 264 + br * 128 + c0) = pk;
    }
    __syncthreads();

    // ---- projection: 16 pix x 128 out, K=256 (bf16 outb) ----
    int lrow = lane & 15;
    int lq = lane >> 4;
    b16x8 af[8];
#pragma unroll
    for (int kk = 0; kk < 8; kk++)
        af[kk] = *(const b16x8*)(agg_s + lrow * 264 + (kk * 4 + lq) * 8);
#pragma unroll
    for (int i = 0; i < 2; i++) {
        int o = (wv + 4 * i) * 16 + lrow;
        const bf16* wrow = outb + (size_t)o * 256;
        f32x4 acc4 = {0.f, 0.f, 0.f, 0.f};
#pragma unroll
        for (int kk = 0; kk < 8; kk++)
            acc4 = __builtin_amdgcn_mfma_f32_16x16x32_bf16(af[kk], *(const b16x8*)(wrow + (kk * 4 + lq) * 8), acc4, 0, 0, 0);
        float bias = out_b[o];
        f32x4 st;
#pragma unroll
        for (int r = 0; r < 4; r++) st[r] = acc4[r] + bias;
        int hw0 = pixbase + lq * 4 - rowbase;       // pix = pixbase + lq*4 + r -> consecutive hw
        *(f32x4*)(out + (size_t)b * (128 * HWs) + (size_t)o * HWs + hw0) = st;
    }
}

extern "C" void kernel_launch(void* const* d_in, const int* in_sizes, int n_in,
                              void* d_out, int out_size, void* d_ws, size_t ws_size,
                              hipStream_t stream)
{
    const float* mask      = (const float*)d_in[0];
    const float* match     = (const float*)d_in[1];
    const float* context   = (const float*)d_in[2];
    const float* geometric = (const float*)d_in[3];
    const float* anc_c     = (const float*)d_in[4];
    const float* anc_g     = (const float*)d_in[5];
    const float* ln_g  = (const float*)d_in[6];
    const float* ln_b  = (const float*)d_in[7];
    const float* lnc_g = (const float*)d_in[8];
    const float* lnc_b = (const float*)d_in[9];
    const float* lng_g = (const float*)d_in[10];
    const float* lng_b = (const float*)d_in[11];
    const float* wc_w  = (const float*)d_in[12];
    const float* wc_b  = (const float*)d_in[13];
    const float* wg_w  = (const float*)d_in[14];
    const float* wg_b  = (const float*)d_in[15];
    const float* vc_w  = (const float*)d_in[16];
    const float* vc_b  = (const float*)d_in[17];
    const float* vg_w  = (const float*)d_in[18];
    const float* vg_b  = (const float*)d_in[19];
    const float* out_w = (const float*)d_in[20];
    const float* out_b = (const float*)d_in[21];
    const float* kpc_w = (const float*)d_in[22];
    const float* kpc_b = (const float*)d_in[23];
    const float* kpg_w = (const float*)d_in[24];
    const float* kpg_b = (const float*)d_in[25];

    // d_ws layout
    char* w = (char*)d_ws;
    unsigned char* ctx8 = (unsigned char*)(w);            //  3,276,800 B (fp8)
    unsigned char* geo8 = (unsigned char*)(w + 3276800);  //  3,276,800 B
    bf16*  wts_g    = (bf16*)(w + 6553600);               //  7,372,800 B
    bf16*  wbuf     = (bf16*)(w + 13926400);              //    172,544 B
    float* bias176  = (float*)(w + 14098944);             //        704 B

    float* outp = (float*)d_out;
    float* kp_out = outp + (size_t)2 * 128 * HWs;         // outputs are f32 (ref dtype)

    k_prep<<<(NW_BF16 + 176 + 255) / 256, 256, 0, stream>>>(
        vc_w, vg_w, wc_w, wg_w, kpc_w, kpg_w, out_w,
        wc_b, wg_b, kpc_b, kpg_b, wbuf, bias176);
    k_stage1<<<2400, 256, 0, stream>>>(match, context, geometric,
                                       ln_g, ln_b, lnc_g, lnc_b, lng_g, lng_b,
                                       vc_b, vg_b, wbuf, bias176,
                                       anc_c, anc_g,
                                       ctx8, geo8, wts_g, kp_out);
    k_fuse<<<1600, 256, 0, stream>>>(ctx8, geo8, wts_g, kp_out, mask,
                                     wbuf + OFF_OUTB, out_b, outp);
}